// Round 6
// baseline (2553.696 us; speedup 1.0000x reference)
//
#include <hip/hip_runtime.h>

// LSTM forward, persistent-kernel, R12:
//   R10/R11 post-mortem: clean-line publish hit its WRITE_SIZE target
//   (150->85-90MB) but cost time (2276->2425/2434us) -> store-drain acks were
//   never the critical term; the Hstg publish serialization was a net loss.
//   The remaining chain is STRUCTURE: 3 barriers/step (one draining
//   ppart/prefetch that aren't on the inter-block dependency) + single-wave
//   poll broadcast via barrier.
//   R12: the flag protocol already proves what barriers #2/#3 re-prove:
//     - sibling flag >= t  ==> sibling published ==> its Hsm ds_reads done
//       ==> safe to overwrite Hsm next step (no post-poll barrier needed);
//     - producer can't publish t+2 before all consumers flagged t+1 (its own
//       end-of-t+1 poll waits on them) ==> double buffer self-protects.
//   So: ONE barrier per step (#1, drains the H-DMA for cross-wave LDS
//   visibility). Per-wave: R6-proven scattered 2B publish -> own vmcnt(0)
//   (only publish outstanding) -> per-wave flag (128 x 64B-stride) ->
//   prefetch + ppart in the poll window -> all-lane poll of 128 flags
//   (2/lane + __all). Core compute identical to R6.

#define NB   128
#define SEQ  512
#define BATCH 64
#define DIM  256
#define HU   1024
#define ROWU 1032   // u16 row stride: 2064 B = 16 mod 128 -> b128 2-way (free)

typedef unsigned short u16;
typedef unsigned int   u32;
typedef unsigned long long u64;
typedef __attribute__((ext_vector_type(8))) short  short8;
typedef __attribute__((ext_vector_type(4))) float  f32x4;

typedef const __attribute__((address_space(1))) void* gptr_t;
typedef __attribute__((address_space(3))) void*       lptr_t;

__device__ __forceinline__ u16 f2bf(float x) {
  u32 u = __float_as_uint(x);
  u32 r = (u + 0x7FFFu + ((u >> 16) & 1u)) >> 16;   // RNE
  return (u16)r;
}
__device__ __forceinline__ float sigf(float x)  { return 1.0f / (1.0f + __expf(-x)); }
__device__ __forceinline__ float tanhfast(float x) { return 1.0f - 2.0f / (1.0f + __expf(2.0f * x)); }
__device__ __forceinline__ short8 cv8(uint4 v) {
  union { uint4 d; short8 s; } u; u.d = v; return u.s;
}
__device__ __forceinline__ u32 ld_ag(const u32* p) {
  return __hip_atomic_load(p, __ATOMIC_RELAXED, __HIP_MEMORY_SCOPE_AGENT);
}
__device__ __forceinline__ void st_ag_u32(u32* p, u32 v) {
  __hip_atomic_store(p, v, __ATOMIC_RELAXED, __HIP_MEMORY_SCOPE_AGENT);
}

// ---------------- prologue kernels ----------------

__global__ void k_prep(const float* __restrict__ H0, u16* __restrict__ Hbuf0,
                       u32* __restrict__ flags) {
  int i = blockIdx.x * 256 + threadIdx.x;
  if (i < 8192) flags[i] = 0u;    // 4bb x 32bj x 4wv flags, 64B stride
  Hbuf0[i] = f2bf(H0[i]);         // i < 65536 == BATCH*HU
}

__global__ void k_xconv(const float* __restrict__ in, u16* __restrict__ out) {
  int i = blockIdx.x * 256 + threadIdx.x;
  float4 v = ((const float4*)in)[i];
  ushort4 o;
  o.x = f2bf(v.x); o.y = f2bf(v.y); o.z = f2bf(v.z); o.w = f2bf(v.w);
  ((ushort4*)out)[i] = o;
}

// Wpack[bj(32)][nt(8)][kc(40)][lane(64)][8] bf16 : MFMA B-fragment order.
// local col c = nt*16 + (lane&15) in [0,128):
//   h_high=c>>5, gate=(c>>3)&3, h_low=c&7, h = bj*32 + h_high*8 + h_low
__global__ void k_pack(const float* __restrict__ Wxi, const float* __restrict__ Whi,
                       const float* __restrict__ Wxf, const float* __restrict__ Whf,
                       const float* __restrict__ Wxo, const float* __restrict__ Who,
                       const float* __restrict__ Wxc, const float* __restrict__ Whc,
                       u16* __restrict__ Wpack) {
  int tid  = blockIdx.x * 256 + threadIdx.x;   // < 32*8*40*64 = 655360
  int lane = tid & 63;
  int kc   = (tid >> 6) % 40;
  int nt   = ((tid >> 6) / 40) & 7;
  int bj   = (tid >> 6) / 320;
  int c    = nt * 16 + (lane & 15);
  int gate = (c >> 3) & 3;
  int h    = bj * 32 + (c >> 5) * 8 + (c & 7);
  const float* Wx = (gate == 0) ? Wxi : (gate == 1) ? Wxf : (gate == 2) ? Wxo : Wxc;
  const float* Wh = (gate == 0) ? Whi : (gate == 1) ? Whf : (gate == 2) ? Who : Whc;
  int kbase = kc * 32 + ((lane >> 4) << 3);
  u16 tmp[8];
#pragma unroll
  for (int e = 0; e < 8; e++) {
    int k = kbase + e;
    float v = (k < DIM) ? Wx[k * HU + h] : Wh[(k - DIM) * HU + h];
    tmp[e] = f2bf(v);
  }
  *(uint4*)(Wpack + (size_t)tid * 8) = *(uint4*)tmp;
}

// pred[b,t] = bd + sum_{g<128} part[t*8192 + g*64 + b];  32768 threads
__global__ void k_predsum(const float* __restrict__ part, const float* __restrict__ bd,
                          float* __restrict__ pred) {
  int i = blockIdx.x * 256 + threadIdx.x;
  int b = i & 63, t = i >> 6;
  float s = bd[0];
  const float* p0 = part + (size_t)t * NB * 64 + b;
#pragma unroll 8
  for (int jj = 0; jj < NB; jj++) s += p0[jj * 64];
  pred[b * SEQ + t] = s;
}

// ---------------- main persistent kernel ----------------

struct MainParams {
  const u16* __restrict__ xbf;     // (B,S,D) bf16
  const u16* __restrict__ Wpack;   // [32][8][40][64][8] bf16
  u16* __restrict__ Hbuf;          // [2][B][HU] bf16 (double buffer)
  const float* __restrict__ C0;
  const float* __restrict__ Wd;
  const float* __restrict__ bi;
  const float* __restrict__ bfg;
  const float* __restrict__ bo;
  const float* __restrict__ bc;
  float* __restrict__ ppart;       // [SEQ][32bj][4wv][64b] pred partials
  float* __restrict__ Hf;          // [B][HU]
  float* __restrict__ Cf;          // [B][HU]
  u32* __restrict__ flags;         // [(bb*128 + bj*4 + wv)*16]  (64B stride)
};

__global__ __launch_bounds__(256, 1) void lstm_main(MainParams p) {
  __shared__ __align__(16) u16 Hsm[16 * ROWU];   // 33024 B

  const int tid  = threadIdx.x;
  const int wv   = tid >> 6, lane = tid & 63;
  const int bj   = blockIdx.x >> 2, bb = blockIdx.x & 3;
  const int q    = lane >> 4;              // row quad
  const int q8   = q * 8;                  // k sub-offset in frag
  const int m16  = lane & 15;
  const int hl   = lane & 7;
  const bool hiH = (lane & 8) != 0;        // f/c-holder half

  const int hglob = bj * 32 + wv * 8 + hl; // this thread's h column
  const int row0  = 16 * bb;               // block's first batch row

  // resident weight B-fragments: wave wv owns n-tiles {2wv, 2wv+1}, full K.
  short8 wx[8][2], wh[32][2];
  {
    const u16* wbase = p.Wpack + ((size_t)bj * 8 + 2 * wv) * (40 * 512) + lane * 8;
#pragma unroll
    for (int kc = 0; kc < 8; kc++)
#pragma unroll
      for (int ntl = 0; ntl < 2; ntl++)
        wx[kc][ntl] = *(const short8*)(wbase + ((size_t)ntl * 40 + kc) * 512);
#pragma unroll
    for (int kc = 0; kc < 32; kc++)
#pragma unroll
      for (int ntl = 0; ntl < 2; ntl++)
        wh[kc][ntl] = *(const short8*)(wbase + ((size_t)ntl * 40 + 8 + kc) * 512);
  }

  // per-thread epilogue state: 4 rows (q*4+r), one h
  const float bI = p.bi[hglob],  bF = p.bfg[hglob];
  const float bO = p.bo[hglob],  bC = p.bc[hglob];
  const float wdv = p.Wd[hglob];
  float Cst[4], Hst[4];
#pragma unroll
  for (int r = 0; r < 4; r++) {
    Cst[r] = p.C0[(row0 + q * 4 + r) * HU + hglob];
    Hst[r] = 0.f;
  }

  // LDS read base for A-frags (m = lane&15 -> local row)
  const u16* Aw = Hsm + m16 * ROWU + q8;

  // this wave's flag + the two flags each lane polls (128 flags of group bb)
  u32* myflag = p.flags + ((size_t)(bb * 128 + bj * 4 + wv) << 4);
  const u32* pf1 = p.flags + ((size_t)(bb * 128 + lane) << 4);
  const u32* pf2 = p.flags + ((size_t)(bb * 128 + 64 + lane) << 4);

  // x fragments for t=0: row = row0 + m16, k = kc*32 + q8
  uint4 ax[8];
#pragma unroll
  for (int kc = 0; kc < 8; kc++)
    ax[kc] = *(const uint4*)(p.xbf + ((size_t)((row0 + m16) * SEQ + 0)) * DIM
                             + kc * 32 + q8);

#pragma unroll 1
  for (int t = 0; t < SEQ; t++) {
    const int rb = t & 1;
    const u16* Hr = p.Hbuf + (size_t)rb * (BATCH * HU);
    u16*       Hw = p.Hbuf + (size_t)(rb ^ 1) * (BATCH * HU);

    // ---- issue H staging: wave wv -> segments [8wv, 8wv+8) of 32 ----
    // segment s: row = s>>1, cols [(s&1)*512, +512); aux=17 (LLC-coherent DMA)
#pragma unroll
    for (int i = 0; i < 8; i++) {
      int s = wv * 8 + i, row = s >> 1, half = s & 1;
      const u16* g = Hr + (size_t)(row0 + row) * HU + half * 512 + lane * 8;
      __builtin_amdgcn_global_load_lds((gptr_t)(const void*)g,
          (lptr_t)(void*)(Hsm + row * ROWU + half * 512), 16, 0, 17);
    }

    // ---- x-phase MFMAs (in the shadow of DMA latency) ----
    f32x4 acc[2][4];
#pragma unroll
    for (int ntl = 0; ntl < 2; ntl++)
#pragma unroll
      for (int c = 0; c < 4; c++) acc[ntl][c] = (f32x4){0.f, 0.f, 0.f, 0.f};
#pragma unroll
    for (int kc = 0; kc < 8; kc++) {
      short8 af = cv8(ax[kc]);
      acc[0][kc & 3] = __builtin_amdgcn_mfma_f32_16x16x32_bf16(af, wx[kc][0], acc[0][kc & 3], 0, 0, 0);
      acc[1][kc & 3] = __builtin_amdgcn_mfma_f32_16x16x32_bf16(af, wx[kc][1], acc[1][kc & 3], 0, 0, 0);
    }

    __syncthreads();   // #1 (only barrier): drains DMA -> Hsm complete

    // ---- H-phase MFMAs from LDS (full K per wave, 2 n-tiles) ----
#pragma unroll
    for (int kc = 0; kc < 32; kc++) {
      short8 af = *(const short8*)(Aw + kc * 32);
      acc[0][kc & 3] = __builtin_amdgcn_mfma_f32_16x16x32_bf16(af, wh[kc][0], acc[0][kc & 3], 0, 0, 0);
      acc[1][kc & 3] = __builtin_amdgcn_mfma_f32_16x16x32_bf16(af, wh[kc][1], acc[1][kc & 3], 0, 0, 0);
    }

    // ---- gate combine: ntl=0 -> {i,f}, ntl=1 -> {o,c}; swap via shfl_xor(8) ----
    f32x4 g01 = (acc[0][0] + acc[0][1]) + (acc[0][2] + acc[0][3]);
    f32x4 g23 = (acc[1][0] + acc[1][1]) + (acc[1][2] + acc[1][3]);

    float pr[4];
#pragma unroll
    for (int r = 0; r < 4; r++) {
      float u0 = g01[r], u1 = g23[r];
      float v0 = __shfl_xor(u0, 8);
      float v1 = __shfl_xor(u1, 8);
      float gi = hiH ? v0 : u0, gf = hiH ? u0 : v0;
      float go = hiH ? v1 : u1, gc = hiH ? u1 : v1;
      float iv = sigf(gi + bI), fv = sigf(gf + bF);
      float ov = sigf(go + bO), ct = tanhfast(gc + bC);
      Cst[r] = fv * Cst[r] + iv * ct;
      Hst[r] = ov * tanhfast(Cst[r]);
      pr[r]  = Hst[r] * wdv;
    }

    // ---- publish H_t (R6-proven: bit3==0 lanes, 2B agent stores) ----
    if (!hiH) {
#pragma unroll
      for (int r = 0; r < 4; r++)
        __hip_atomic_store(Hw + (size_t)(row0 + q * 4 + r) * HU + hglob,
                           f2bf(Hst[r]), __ATOMIC_RELAXED, __HIP_MEMORY_SCOPE_AGENT);
    }

    // pred shfl-reduce over 8 h (covers publish store latency)
#pragma unroll
    for (int r = 0; r < 4; r++) {
      pr[r] += __shfl_xor(pr[r], 1);
      pr[r] += __shfl_xor(pr[r], 2);
      pr[r] += __shfl_xor(pr[r], 4);
    }

    // wait for THIS WAVE's publish only (DMA/prefetch/ppart long drained)
    asm volatile("s_waitcnt vmcnt(0)" ::: "memory");

    // per-wave flag
    const u32 tf = (u32)(t + 1);
    if (lane == 0) st_ag_u32(myflag, tf);

    // ---- poll-window work (NOT on the flag path) ----
    {
      const int tn = (t + 1 < SEQ) ? t + 1 : t;
#pragma unroll
      for (int kc = 0; kc < 8; kc++)
        ax[kc] = *(const uint4*)(p.xbf + ((size_t)((row0 + m16) * SEQ + tn)) * DIM
                                 + kc * 32 + q8);
    }
    if (m16 == 0) {
      float4 st = {pr[0], pr[1], pr[2], pr[3]};
      *(float4*)(p.ppart + (((size_t)t * 32 + bj) * 4 + wv) * 64 + row0 + q * 4) = st;
    }

    // ---- per-wave poll: every wave watches all 128 (producer,wave) flags.
    // Sibling flag >= tf  ==> its Hsm reads are done ==> next-iter DMA safe.
    // Producer can't reach t+2 publish before we flag t+1 ==> dbuf safe.
    for (;;) {
      u32 a = ld_ag(pf1), b = ld_ag(pf2);
      if (__all(a >= tf && b >= tf)) break;
      __builtin_amdgcn_s_sleep(1);
    }
  }

  // finals
  if (!hiH) {
#pragma unroll
    for (int r = 0; r < 4; r++) {
      int row = row0 + q * 4 + r;
      p.Hf[row * HU + hglob] = Hst[r];
      p.Cf[row * HU + hglob] = Cst[r];
    }
  }
}

// ---------------- launch ----------------

extern "C" void kernel_launch(void* const* d_in, const int* in_sizes, int n_in,
                              void* d_out, int out_size, void* d_ws, size_t ws_size,
                              hipStream_t stream) {
  const float* inputs = (const float*)d_in[0];
  const float* H0  = (const float*)d_in[1];
  const float* C0  = (const float*)d_in[2];
  const float* Wxi = (const float*)d_in[3];
  const float* Whi = (const float*)d_in[4];
  const float* bi  = (const float*)d_in[5];
  const float* Wxf = (const float*)d_in[6];
  const float* Whf = (const float*)d_in[7];
  const float* bf_ = (const float*)d_in[8];
  const float* Wxo = (const float*)d_in[9];
  const float* Who = (const float*)d_in[10];
  const float* bo  = (const float*)d_in[11];
  const float* Wxc = (const float*)d_in[12];
  const float* Whc = (const float*)d_in[13];
  const float* bc  = (const float*)d_in[14];
  const float* Wd  = (const float*)d_in[15];
  const float* bd  = (const float*)d_in[16];

  char* ws = (char*)d_ws;
  u32*   flags = (u32*)ws;                                       // 32768 B
  u16*   Wpack = (u16*)(ws + 32768);                             // 10485760 B
  u16*   xbf   = (u16*)(ws + 32768 + 10485760);                  // 16777216 B
  u16*   Hbuf  = (u16*)(ws + 32768 + 10485760 + 16777216);       // 262144 B
  float* ppart = (float*)(ws + 32768 + 10485760 + 16777216 + 262144); // 16777216 B

  float* pred = (float*)d_out;
  float* Hf   = pred + BATCH * SEQ;
  float* Cf   = Hf + BATCH * HU;

  k_prep<<<256, 256, 0, stream>>>(H0, Hbuf, flags);
  k_xconv<<<8192, 256, 0, stream>>>(inputs, xbf);
  k_pack<<<2560, 256, 0, stream>>>(Wxi, Whi, Wxf, Whf, Wxo, Who, Wxc, Whc, Wpack);

  MainParams prm{xbf, Wpack, Hbuf, C0, Wd, bi, bf_, bo, bc, ppart, Hf, Cf, flags};
  lstm_main<<<dim3(NB), dim3(256), 0, stream>>>(prm);

  k_predsum<<<128, 256, 0, stream>>>(ppart, bd, pred);
}

// Round 7
// 2308.147 us; speedup vs baseline: 1.1064x; 1.1064x over previous
//
#include <hip/hip_runtime.h>

// LSTM forward, persistent-kernel, R13:
//   R10-R12 post-mortem: every sync-structure deviation from R6 regressed
//   (R10 2425, R11 2434, R12 2491 vs R6 2276). Per-step time ~4.45us is
//   insensitive to barrier count / flag layout / drain scope -> remaining
//   time = LLC RTs + skew + per-step serial instruction overhead.
//   R13 = R6 byte-exact sync skeleton (3 barriers, tid0 flag store, tid<32
//   poll, 32x64B flags, aux=17 DMA, scattered-store position) + two local
//   cuts that do NOT touch the sync structure:
//   1) packed publish: both 16-lane halves hold identical Hst (gate-swap
//      redundancy) -> halves split rows, 2x shfl_xor col-pack, lanes
//      hl in {0,4} store 8B. 32x8B dword stores/wave vs 128x2B sub-dword
//      device-scope stores -> dword-granular LLC writes, shorter drain at
//      barrier #2.
//   2) t-loop unroll x2: rb compile-time per copy -> Hbuf/flag/ppart/DMA
//      addresses loop-carried instead of per-step size_t recomputation ->
//      cuts serial VALU (13% busy) on the chain.

#define NB   128
#define SEQ  512
#define BATCH 64
#define DIM  256
#define HU   1024
#define ROWU 1032   // u16 row stride: 2064 B = 16 mod 128 -> b128 2-way (free)

typedef unsigned short u16;
typedef unsigned int   u32;
typedef unsigned long long u64;
typedef __attribute__((ext_vector_type(8))) short  short8;
typedef __attribute__((ext_vector_type(4))) float  f32x4;

typedef const __attribute__((address_space(1))) void* gptr_t;
typedef __attribute__((address_space(3))) void*       lptr_t;

__device__ __forceinline__ u16 f2bf(float x) {
  u32 u = __float_as_uint(x);
  u32 r = (u + 0x7FFFu + ((u >> 16) & 1u)) >> 16;   // RNE
  return (u16)r;
}
__device__ __forceinline__ float sigf(float x)  { return 1.0f / (1.0f + __expf(-x)); }
__device__ __forceinline__ float tanhfast(float x) { return 1.0f - 2.0f / (1.0f + __expf(2.0f * x)); }
__device__ __forceinline__ short8 cv8(uint4 v) {
  union { uint4 d; short8 s; } u; u.d = v; return u.s;
}

// ---------------- prologue kernels ----------------

__global__ void k_prep(const float* __restrict__ H0, u16* __restrict__ Hbuf0,
                       u32* __restrict__ flags) {
  int i = blockIdx.x * 256 + threadIdx.x;
  if (i < 2048) flags[i] = 0u;
  Hbuf0[i] = f2bf(H0[i]);   // i < 65536 == BATCH*HU
}

__global__ void k_xconv(const float* __restrict__ in, u16* __restrict__ out) {
  int i = blockIdx.x * 256 + threadIdx.x;
  float4 v = ((const float4*)in)[i];
  ushort4 o;
  o.x = f2bf(v.x); o.y = f2bf(v.y); o.z = f2bf(v.z); o.w = f2bf(v.w);
  ((ushort4*)out)[i] = o;
}

// Wpack[bj(32)][nt(8)][kc(40)][lane(64)][8] bf16 : MFMA B-fragment order.
__global__ void k_pack(const float* __restrict__ Wxi, const float* __restrict__ Whi,
                       const float* __restrict__ Wxf, const float* __restrict__ Whf,
                       const float* __restrict__ Wxo, const float* __restrict__ Who,
                       const float* __restrict__ Wxc, const float* __restrict__ Whc,
                       u16* __restrict__ Wpack) {
  int tid  = blockIdx.x * 256 + threadIdx.x;   // < 32*8*40*64 = 655360
  int lane = tid & 63;
  int kc   = (tid >> 6) % 40;
  int nt   = ((tid >> 6) / 40) & 7;
  int bj   = (tid >> 6) / 320;
  int c    = nt * 16 + (lane & 15);
  int gate = (c >> 3) & 3;
  int h    = bj * 32 + (c >> 5) * 8 + (c & 7);
  const float* Wx = (gate == 0) ? Wxi : (gate == 1) ? Wxf : (gate == 2) ? Wxo : Wxc;
  const float* Wh = (gate == 0) ? Whi : (gate == 1) ? Whf : (gate == 2) ? Who : Whc;
  int kbase = kc * 32 + ((lane >> 4) << 3);
  u16 tmp[8];
#pragma unroll
  for (int e = 0; e < 8; e++) {
    int k = kbase + e;
    float v = (k < DIM) ? Wx[k * HU + h] : Wh[(k - DIM) * HU + h];
    tmp[e] = f2bf(v);
  }
  *(uint4*)(Wpack + (size_t)tid * 8) = *(uint4*)tmp;
}

// pred[b,t] = bd + sum_{g<128} part[t*8192 + g*64 + b];  32768 threads
__global__ void k_predsum(const float* __restrict__ part, const float* __restrict__ bd,
                          float* __restrict__ pred) {
  int i = blockIdx.x * 256 + threadIdx.x;
  int b = i & 63, t = i >> 6;
  float s = bd[0];
  const float* p0 = part + (size_t)t * NB * 64 + b;
#pragma unroll 8
  for (int jj = 0; jj < NB; jj++) s += p0[jj * 64];
  pred[b * SEQ + t] = s;
}

// ---------------- main persistent kernel ----------------

struct MainParams {
  const u16* __restrict__ xbf;     // (B,S,D) bf16
  const u16* __restrict__ Wpack;   // [32][8][40][64][8] bf16
  u16* __restrict__ Hbuf;          // [2][B][HU] bf16 (double buffer)
  const float* __restrict__ C0;
  const float* __restrict__ Wd;
  const float* __restrict__ bi;
  const float* __restrict__ bfg;
  const float* __restrict__ bo;
  const float* __restrict__ bc;
  float* __restrict__ ppart;       // [SEQ][32bj][4wv][64b] pred partials
  float* __restrict__ Hf;          // [B][HU]
  float* __restrict__ Cf;          // [B][HU]
  u32* __restrict__ flags;         // [4bb][32bj] stride-16 u32
};

__global__ __launch_bounds__(256, 1) void lstm_main(MainParams p) {
  __shared__ __align__(16) u16 Hsm[16 * ROWU];   // 33024 B

  const int tid  = threadIdx.x;
  const int wv   = tid >> 6, lane = tid & 63;
  const int bj   = blockIdx.x >> 2, bb = blockIdx.x & 3;
  const int q    = lane >> 4;              // row quad
  const int q8   = q * 8;                  // k sub-offset in frag
  const int m16  = lane & 15;
  const int hl   = lane & 7;
  const bool hiH = (lane & 8) != 0;        // f/c-holder half

  const int hglob = bj * 32 + wv * 8 + hl; // this thread's h column
  const int row0  = 16 * bb;               // block's first batch row

  // resident weight B-fragments: wave wv owns n-tiles {2wv, 2wv+1}, full K.
  short8 wx[8][2], wh[32][2];
  {
    const u16* wbase = p.Wpack + ((size_t)bj * 8 + 2 * wv) * (40 * 512) + lane * 8;
#pragma unroll
    for (int kc = 0; kc < 8; kc++)
#pragma unroll
      for (int ntl = 0; ntl < 2; ntl++)
        wx[kc][ntl] = *(const short8*)(wbase + ((size_t)ntl * 40 + kc) * 512);
#pragma unroll
    for (int kc = 0; kc < 32; kc++)
#pragma unroll
      for (int ntl = 0; ntl < 2; ntl++)
        wh[kc][ntl] = *(const short8*)(wbase + ((size_t)ntl * 40 + 8 + kc) * 512);
  }

  // per-thread epilogue state: 4 rows (q*4+r), one h
  const float bI = p.bi[hglob],  bF = p.bfg[hglob];
  const float bO = p.bo[hglob],  bC = p.bc[hglob];
  const float wdv = p.Wd[hglob];
  float Cst[4], Hst[4];
#pragma unroll
  for (int r = 0; r < 4; r++) {
    Cst[r] = p.C0[(row0 + q * 4 + r) * HU + hglob];
    Hst[r] = 0.f;
  }

  // LDS read base for A-frags (m = lane&15 -> local row)
  const u16* Aw = Hsm + m16 * ROWU + q8;

  // x fragments for t=0: row = row0 + m16, k = kc*32 + q8
  uint4 ax[8];
#pragma unroll
  for (int kc = 0; kc < 8; kc++)
    ax[kc] = *(const uint4*)(p.xbf + ((size_t)((row0 + m16) * SEQ + 0)) * DIM
                             + kc * 32 + q8);

  u16* const buf0 = p.Hbuf;
  u16* const buf1 = p.Hbuf + (size_t)BATCH * HU;

  // ---- one timestep, R6-exact skeleton; publish packed to 8B stores ----
#define STEP_BODY(T, Hr, Hw)                                                    \
  {                                                                             \
    _Pragma("unroll")                                                           \
    for (int i = 0; i < 8; i++) {                                               \
      int s = wv * 8 + i, row = s >> 1, half = s & 1;                           \
      const u16* g = (Hr) + (size_t)(row0 + row) * HU + half * 512 + lane * 8;  \
      __builtin_amdgcn_global_load_lds((gptr_t)(const void*)g,                  \
          (lptr_t)(void*)(Hsm + row * ROWU + half * 512), 16, 0, 17);           \
    }                                                                           \
    f32x4 acc[2][4];                                                            \
    _Pragma("unroll")                                                           \
    for (int ntl = 0; ntl < 2; ntl++)                                           \
      _Pragma("unroll")                                                         \
      for (int c = 0; c < 4; c++) acc[ntl][c] = (f32x4){0.f, 0.f, 0.f, 0.f};    \
    _Pragma("unroll")                                                           \
    for (int kc = 0; kc < 8; kc++) {                                            \
      short8 af = cv8(ax[kc]);                                                  \
      acc[0][kc & 3] = __builtin_amdgcn_mfma_f32_16x16x32_bf16(af, wx[kc][0], acc[0][kc & 3], 0, 0, 0); \
      acc[1][kc & 3] = __builtin_amdgcn_mfma_f32_16x16x32_bf16(af, wx[kc][1], acc[1][kc & 3], 0, 0, 0); \
    }                                                                           \
    __syncthreads();  /* #1: DMA drained, Hsm complete */                       \
    {                                                                           \
      int tn = (T) + 1; if (tn >= SEQ) tn = SEQ - 1;                            \
      _Pragma("unroll")                                                         \
      for (int kc = 0; kc < 8; kc++)                                            \
        ax[kc] = *(const uint4*)(p.xbf + ((size_t)((row0 + m16) * SEQ + tn)) * DIM \
                                 + kc * 32 + q8);                               \
    }                                                                           \
    _Pragma("unroll")                                                           \
    for (int kc = 0; kc < 32; kc++) {                                           \
      short8 af = *(const short8*)(Aw + kc * 32);                               \
      acc[0][kc & 3] = __builtin_amdgcn_mfma_f32_16x16x32_bf16(af, wh[kc][0], acc[0][kc & 3], 0, 0, 0); \
      acc[1][kc & 3] = __builtin_amdgcn_mfma_f32_16x16x32_bf16(af, wh[kc][1], acc[1][kc & 3], 0, 0, 0); \
    }                                                                           \
    f32x4 g01 = (acc[0][0] + acc[0][1]) + (acc[0][2] + acc[0][3]);              \
    f32x4 g23 = (acc[1][0] + acc[1][1]) + (acc[1][2] + acc[1][3]);              \
    float pr[4];                                                                \
    _Pragma("unroll")                                                           \
    for (int r = 0; r < 4; r++) {                                               \
      float u0 = g01[r], u1 = g23[r];                                           \
      float v0 = __shfl_xor(u0, 8);                                             \
      float v1 = __shfl_xor(u1, 8);                                             \
      float gi = hiH ? v0 : u0, gf = hiH ? u0 : v0;                             \
      float go = hiH ? v1 : u1, gc = hiH ? u1 : v1;                             \
      float iv = sigf(gi + bI), fv = sigf(gf + bF);                             \
      float ov = sigf(go + bO), ct = tanhfast(gc + bC);                         \
      Cst[r] = fv * Cst[r] + iv * ct;                                           \
      Hst[r] = ov * tanhfast(Cst[r]);                                           \
      pr[r]  = Hst[r] * wdv;                                                    \
    }                                                                           \
    /* packed publish: halves split rows; 2 shfl packs; hl in {0,4} store 8B */ \
    {                                                                           \
      u32 b0 = f2bf(Hst[hiH ? 2 : 0]);                                         \
      u32 b1 = f2bf(Hst[hiH ? 3 : 1]);                                         \
      u32 s0 = (u32)__shfl_xor((int)b0, 1);                                     \
      u32 s1 = (u32)__shfl_xor((int)b1, 1);                                     \
      u32 p0 = (b0 & 0xFFFFu) | (s0 << 16);                                     \
      u32 p1 = (b1 & 0xFFFFu) | (s1 << 16);                                     \
      u32 q0 = (u32)__shfl_xor((int)p0, 2);                                     \
      u32 q1 = (u32)__shfl_xor((int)p1, 2);                                     \
      if ((hl & 3) == 0) {                                                      \
        const int rr = row0 + q * 4 + (hiH ? 2 : 0);                            \
        u64 v0 = (u64)p0 | ((u64)q0 << 32);                                     \
        u64 v1 = (u64)p1 | ((u64)q1 << 32);                                     \
        __hip_atomic_store((u64*)((Hw) + (size_t)rr * HU + hglob), v0,          \
                           __ATOMIC_RELAXED, __HIP_MEMORY_SCOPE_AGENT);         \
        __hip_atomic_store((u64*)((Hw) + (size_t)(rr + 1) * HU + hglob), v1,    \
                           __ATOMIC_RELAXED, __HIP_MEMORY_SCOPE_AGENT);         \
      }                                                                         \
    }                                                                           \
    _Pragma("unroll")                                                           \
    for (int r = 0; r < 4; r++) {                                               \
      pr[r] += __shfl_xor(pr[r], 1);                                            \
      pr[r] += __shfl_xor(pr[r], 2);                                            \
      pr[r] += __shfl_xor(pr[r], 4);                                            \
    }                                                                           \
    if (m16 == 0) {                                                             \
      float4 st = {pr[0], pr[1], pr[2], pr[3]};                                 \
      *(float4*)(p.ppart + (((size_t)(T) * 32 + bj) * 4 + wv) * 64 + row0 + q * 4) = st; \
    }                                                                           \
    __syncthreads();  /* #2: drains publish/ppart/prefetch before flag */       \
    if (tid == 0)                                                               \
      __hip_atomic_store(p.flags + (bb * 32 + bj) * 16, (u32)((T) + 1),         \
                         __ATOMIC_RELAXED, __HIP_MEMORY_SCOPE_AGENT);           \
    if (tid < 32) {                                                             \
      const u32* f = p.flags + (bb * 32 + tid) * 16;                            \
      while (__hip_atomic_load(f, __ATOMIC_RELAXED, __HIP_MEMORY_SCOPE_AGENT) < (u32)((T) + 1)) \
        __builtin_amdgcn_s_sleep(1);                                            \
    }                                                                           \
    __syncthreads();  /* #3 */                                                  \
  }

#pragma unroll 1
  for (int t = 0; t < SEQ; t += 2) {
    STEP_BODY(t,     buf0, buf1)   // even: read buf0, write buf1
    STEP_BODY(t + 1, buf1, buf0)   // odd:  read buf1, write buf0
  }
#undef STEP_BODY

  // finals
  if (!hiH) {
#pragma unroll
    for (int r = 0; r < 4; r++) {
      int row = row0 + q * 4 + r;
      p.Hf[row * HU + hglob] = Hst[r];
      p.Cf[row * HU + hglob] = Cst[r];
    }
  }
}

// ---------------- launch ----------------

extern "C" void kernel_launch(void* const* d_in, const int* in_sizes, int n_in,
                              void* d_out, int out_size, void* d_ws, size_t ws_size,
                              hipStream_t stream) {
  const float* inputs = (const float*)d_in[0];
  const float* H0  = (const float*)d_in[1];
  const float* C0  = (const float*)d_in[2];
  const float* Wxi = (const float*)d_in[3];
  const float* Whi = (const float*)d_in[4];
  const float* bi  = (const float*)d_in[5];
  const float* Wxf = (const float*)d_in[6];
  const float* Whf = (const float*)d_in[7];
  const float* bf_ = (const float*)d_in[8];
  const float* Wxo = (const float*)d_in[9];
  const float* Who = (const float*)d_in[10];
  const float* bo  = (const float*)d_in[11];
  const float* Wxc = (const float*)d_in[12];
  const float* Whc = (const float*)d_in[13];
  const float* bc  = (const float*)d_in[14];
  const float* Wd  = (const float*)d_in[15];
  const float* bd  = (const float*)d_in[16];

  char* ws = (char*)d_ws;
  u32*   flags = (u32*)ws;                                      // 8192 B
  u16*   Wpack = (u16*)(ws + 8192);                             // 10485760 B
  u16*   xbf   = (u16*)(ws + 8192 + 10485760);                  // 16777216 B
  u16*   Hbuf  = (u16*)(ws + 8192 + 10485760 + 16777216);       // 262144 B
  float* ppart = (float*)(ws + 8192 + 10485760 + 16777216 + 262144); // 16777216 B

  float* pred = (float*)d_out;
  float* Hf   = pred + BATCH * SEQ;
  float* Cf   = Hf + BATCH * HU;

  k_prep<<<256, 256, 0, stream>>>(H0, Hbuf, flags);
  k_xconv<<<8192, 256, 0, stream>>>(inputs, xbf);
  k_pack<<<2560, 256, 0, stream>>>(Wxi, Whi, Wxf, Whf, Wxo, Who, Wxc, Whc, Wpack);

  MainParams prm{xbf, Wpack, Hbuf, C0, Wd, bi, bf_, bo, bc, ppart, Hf, Cf, flags};
  lstm_main<<<dim3(NB), dim3(256), 0, stream>>>(prm);

  k_predsum<<<128, 256, 0, stream>>>(ppart, bd, pred);
}